// Round 4
// baseline (279.013 us; speedup 1.0000x reference)
//
#include <hip/hip_runtime.h>
#include <hip/hip_fp16.h>

// Problem geometry: inputs (B=2, D=64, H=64, W=64, C=32) fp32, C innermost.
// Pass1: Sobel (VALID) -> mag = sqrt(gx^2+gy^2+gz^2) at 62^3 per (b,c)
// Pass2: Sobel on mag -> out = sqrt(gx^2+gy^2) + gz^2 at 60^3
// Result: mean(|out_pred - out_hr|) over 2*32*60^3 = 13,824,000 elems.
//
// R8: async DMA staging (global_load_lds). Model fitting R4-R7: rate =
// waves x bytes-in-flight / latency; register prefetch (R6) fails because
// VGPR cost cancels MLP. global_load_lds holds in-flight planes in LDS at
// zero VGPR cost: one 32KB plane in flight per block = ~85 GB/s/CU of
// latency tolerance vs the ~25 GB/s/CU needed. Both passes: double-buffered
// LDS plane streaming with counted s_waitcnt vmcnt(N) + raw s_barrier
// (never drain to 0 in-loop; __syncthreads would full-drain the prefetch).
// mag is padded to 64-col rows (4KB) so P2 staging is 16B-aligned linear.
// P1: full-row blocks, grid (31,8,2)=496 (~2/CU, matches 64KB-LDS residency).
// P2: half-row tiles, grid (60,15)=900, 32KB LDS, vmcnt(4) cadence.

constexpr int BDIM = 256;
constexpr size_t IN_B = 8388608;   // floats per batch
constexpr int IN_D = 131072;       // floats per z-plane
constexpr int IN_H = 2048;         // floats per y-row
constexpr int M = 62;              // mag spatial dim
constexpr int F = 60;              // final spatial dim
// padded mag: row = 64*32 = 2048 halves (4096 B), plane = 62 rows
constexpr int PMROW = 2048;                      // halves per row
constexpr size_t PPLANE = (size_t)M * PMROW;     // halves per z-plane
constexpr size_t PMAGSZ = (size_t)M * PPLANE;    // halves per buffer (~15 MiB)
constexpr unsigned NPART = 1800;                 // 900 blocks x 2 batches

__device__ __forceinline__ void dma16(const void* g, void* l) {
    __builtin_amdgcn_global_load_lds(
        (const __attribute__((address_space(1))) void*)g,
        (__attribute__((address_space(3))) void*)l, 16, 0, 0);
}

#define WAITBAR(N) do { \
    asm volatile("s_waitcnt vmcnt(" #N ")" ::: "memory"); \
    __builtin_amdgcn_sched_barrier(0); \
    __builtin_amdgcn_s_barrier(); \
    __builtin_amdgcn_sched_barrier(0); \
} while (0)

#define MIDBAR() do { \
    __builtin_amdgcn_sched_barrier(0); \
    __builtin_amdgcn_s_barrier(); \
    __builtin_amdgcn_sched_barrier(0); \
} while (0)

__device__ __forceinline__ float4 ld4(const float* p) {
    return *reinterpret_cast<const float4*>(p);
}
__device__ __forceinline__ float4 ldh4(const __half* p) {
    float2 r = *reinterpret_cast<const float2*>(p);
    const __half2* h = reinterpret_cast<const __half2*>(&r);
    float2 lo = __half22float2(h[0]), hi = __half22float2(h[1]);
    return make_float4(lo.x, lo.y, hi.x, hi.y);
}
__device__ __forceinline__ float4 sm3(float4 a, float4 b, float4 c) {
    return make_float4(a.x + 2.f * b.x + c.x, a.y + 2.f * b.y + c.y,
                       a.z + 2.f * b.z + c.z, a.w + 2.f * b.w + c.w);
}
__device__ __forceinline__ float4 df2(float4 a, float4 c) {
    return make_float4(c.x - a.x, c.y - a.y, c.z - a.z, c.w - a.w);
}

// ===================== Pass 1: input -> fp16 mag (padded) =====================
struct P1W { float4 A[2], B[2], C[2]; };

__device__ __forceinline__ void p1_partials(const float* __restrict__ sb,
                                            int x, int c4, P1W& W)
{
    float4 S[4], D[4];
#pragma unroll
    for (int r = 0; r < 4; ++r) {
        const float* p = sb + r * 2048 + x * 32 + c4;
        float4 a = ld4(p), b = ld4(p + 32), c = ld4(p + 64);
        S[r] = sm3(a, b, c);
        D[r] = df2(a, c);
    }
#pragma unroll
    for (int k = 0; k < 2; ++k) {
        W.A[k] = sm3(S[k], S[k+1], S[k+2]);
        W.B[k] = df2(S[k], S[k+2]);
        W.C[k] = sm3(D[k], D[k+1], D[k+2]);
    }
}

__device__ __forceinline__ void p1_emit4(const P1W& W0, const P1W& W1, const P1W& W2,
                                         __half* __restrict__ mag, int x, int c4,
                                         int z, int y0)
{
#pragma unroll
    for (int k = 0; k < 2; ++k) {
        float4 gx = df2(W0.A[k], W2.A[k]);
        float4 gy = sm3(W0.B[k], W1.B[k], W2.B[k]);
        float4 gz = sm3(W0.C[k], W1.C[k], W2.C[k]);
        float m0 = sqrtf(gx.x * gx.x + gy.x * gy.x + gz.x * gz.x);
        float m1 = sqrtf(gx.y * gx.y + gy.y * gy.y + gz.y * gz.y);
        float m2 = sqrtf(gx.z * gx.z + gy.z * gy.z + gz.z * gz.z);
        float m3 = sqrtf(gx.w * gx.w + gy.w * gy.w + gz.w * gz.w);
        union { __half2 h[2]; float2 f; } u;
        u.h[0] = __floats2half2_rn(m0, m1);
        u.h[1] = __floats2half2_rn(m2, m3);
        *reinterpret_cast<float2*>(
            mag + (size_t)z * PPLANE + (size_t)(y0 + k) * PMROW + x * 32 + c4) = u.f;
    }
}

// grid (31, 8, 2): blockIdx.x = y-tile (2 mag rows), .y = z-chunk of 8, .z = input.
__global__ __launch_bounds__(BDIM) void sobel_mag_v8(
    const float* __restrict__ pred, const float* __restrict__ hr,
    __half* __restrict__ magP, __half* __restrict__ magH,
    int b, unsigned* __restrict__ counter, int zeroCtr)
{
    __shared__ char smem[65536];   // 2 x 32KB plane buffers (4 rows x 8KB)

    if (zeroCtr && blockIdx.x == 0 && blockIdx.y == 0 && blockIdx.z == 0 &&
        threadIdx.x == 0)
        __hip_atomic_store(counter, 0u, __ATOMIC_RELAXED,
                           __HIP_MEMORY_SCOPE_AGENT);

    const int yt = blockIdx.x;             // 0..30
    const int zc = blockIdx.y;             // 0..7
    const float* __restrict__ in  = blockIdx.z ? hr   : pred;
    __half*      __restrict__ mag = blockIdx.z ? magH : magP;
    const int y0 = yt * 2;
    const int z0 = zc * 8;
    const int zn = min(8, M - z0);         // 8 or 6
    const int tid = threadIdx.x;
    const int c4 = (tid & 7) << 2;         // channel base 0..28
    const int xA = tid >> 3;               // 0..31 (always valid, < 62)
    const int xB = xA + 32;                // 32..63
    const bool xBok = xB < M;

    const char* gIn = (const char*)in +
        ((size_t)b * IN_B + (size_t)y0 * IN_H) * 4 + (size_t)tid * 16;

    // stage input plane zz (4 rows x 8KB, contiguous 32KB) into buffer q
    auto ISSUE = [&](int q, int zz) {
        const char* g = gIn + (size_t)min(zz, 63) * (IN_D * 4);
        char* l = smem + q * 32768 + tid * 16;
#pragma unroll
        for (int k = 0; k < 8; ++k)
            dma16(g + k * 4096, l + k * 4096);
    };

    P1W A0, A1, A2, B0, B1, B2;
    auto COMPA = [&](int q, P1W& Wa, P1W& Wb) {
        const float* sb = (const float*)(smem + q * 32768);
        p1_partials(sb, xA, c4, Wa);
        if (xBok) p1_partials(sb, xB, c4, Wb);
    };

    ISSUE(0, z0 + 0); ISSUE(1, z0 + 1);        // 16 in flight
    WAITBAR(8);                                 // buf0 ready
    COMPA(0, A0, B0);
    MIDBAR(); ISSUE(0, z0 + 2);
    WAITBAR(8);                                 // buf1 ready
    COMPA(1, A1, B1);
    MIDBAR(); ISSUE(1, z0 + 3);

    int z = 0;
    while (true) {
        WAITBAR(8);
        COMPA(z & 1, A2, B2);
        p1_emit4(A0, A1, A2, mag, xA, c4, z0 + z, y0);
        if (xBok) p1_emit4(B0, B1, B2, mag, xB, c4, z0 + z, y0);
        MIDBAR(); ISSUE(z & 1, z0 + z + 4);
        if (++z >= zn) break;
        WAITBAR(8);
        COMPA(z & 1, A0, B0);
        p1_emit4(A1, A2, A0, mag, xA, c4, z0 + z, y0);
        if (xBok) p1_emit4(B1, B2, B0, mag, xB, c4, z0 + z, y0);
        MIDBAR(); ISSUE(z & 1, z0 + z + 4);
        if (++z >= zn) break;
        WAITBAR(8);
        COMPA(z & 1, A1, B1);
        p1_emit4(A2, A0, A1, mag, xA, c4, z0 + z, y0);
        if (xBok) p1_emit4(B2, B0, B1, mag, xB, c4, z0 + z, y0);
        MIDBAR(); ISSUE(z & 1, z0 + z + 4);
        if (++z >= zn) break;
    }
    asm volatile("s_waitcnt vmcnt(0)" ::: "memory");
}

// ========== Pass 2: mag -> final, diff, partial sums (DMA-staged) ==========
struct P2W4 { float4 A[2], B[2], C[2]; };

__device__ __forceinline__ void p2_partials(const __half* __restrict__ sb,
                                            int xl, int c4, P2W4& W)
{
    float4 S[4], D[4];
#pragma unroll
    for (int j = 0; j < 4; ++j) {
        const __half* p = sb + j * 1024 + xl * 32 + c4;
        float4 a = ldh4(p), b = ldh4(p + 32), c = ldh4(p + 64);
        S[j] = sm3(a, b, c);
        D[j] = df2(a, c);
    }
#pragma unroll
    for (int k = 0; k < 2; ++k) {
        W.A[k] = sm3(S[k], S[k+1], S[k+2]);
        W.B[k] = df2(S[k], S[k+2]);
        W.C[k] = sm3(D[k], D[k+1], D[k+2]);
    }
}

__device__ __forceinline__ void p2_emit4(const P2W4& P0, const P2W4& P1, const P2W4& P2,
                                         const P2W4& H0, const P2W4& H1, const P2W4& H2,
                                         float& acc)
{
#pragma unroll
    for (int k = 0; k < 2; ++k) {
        float4 gxP = df2(P0.A[k], P2.A[k]);
        float4 gyP = sm3(P0.B[k], P1.B[k], P2.B[k]);
        float4 gzP = sm3(P0.C[k], P1.C[k], P2.C[k]);
        float4 gxH = df2(H0.A[k], H2.A[k]);
        float4 gyH = sm3(H0.B[k], H1.B[k], H2.B[k]);
        float4 gzH = sm3(H0.C[k], H1.C[k], H2.C[k]);
        acc += fabsf((sqrtf(gxP.x*gxP.x + gyP.x*gyP.x) + gzP.x*gzP.x)
                   - (sqrtf(gxH.x*gxH.x + gyH.x*gyH.x) + gzH.x*gzH.x));
        acc += fabsf((sqrtf(gxP.y*gxP.y + gyP.y*gyP.y) + gzP.y*gzP.y)
                   - (sqrtf(gxH.y*gxH.y + gyH.y*gyH.y) + gzH.y*gzH.y));
        acc += fabsf((sqrtf(gxP.z*gxP.z + gyP.z*gyP.z) + gzP.z*gzP.z)
                   - (sqrtf(gxH.z*gxH.z + gyH.z*gyH.z) + gzH.z*gzH.z));
        acc += fabsf((sqrtf(gxP.w*gxP.w + gyP.w*gyP.w) + gzP.w*gzP.w)
                   - (sqrtf(gxH.w*gxH.w + gyH.w*gyH.w) + gzH.w*gzH.w));
    }
}

// grid (60, 15): blockIdx.x = xt*1 + yt*2 (xt in {0,1}, yt 0..29), .y = z-chunk of 4.
__global__ __launch_bounds__(BDIM) void sobel2_v8(
    const __half* __restrict__ magP, const __half* __restrict__ magH,
    int b, float* __restrict__ partial, unsigned* __restrict__ counter,
    float* __restrict__ out)
{
    __shared__ char smem[32768];   // 2 x 16KB: [inpP 4 rows | inpH 4 rows] x 2KB

    const int xt = blockIdx.x & 1, yt = blockIdx.x >> 1;  // yt 0..29
    const int zc = blockIdx.y;                            // 0..14
    const int x0 = xt * 30;
    const int y0 = yt * 2;
    const int z0 = zc * 4;
    const int tid = threadIdx.x;
    const int c4 = (tid & 7) << 2;
    const int xl = tid >> 3;            // 0..31, valid outputs xl < 30
    const bool xok = xl < 30;

    const char* gPbase = (const char*)magP + (size_t)y0 * 4096 + (size_t)x0 * 64;
    const char* gHbase = (const char*)magH + (size_t)y0 * 4096 + (size_t)x0 * 64;
    const int sub = tid >> 7;           // 0/1
    const int off = (tid & 127) * 16;   // 0..2032

    // stage mag plane zz (rows y0..y0+3, cols x0..x0+31, P and H) into buffer q
    auto ISSUE = [&](int q, int zz) {
        const size_t pb = (size_t)min(zz, M - 1) * (PPLANE * 2);
        const char* gP = gPbase + pb;
        const char* gH = gHbase + pb;
        char* lb = smem + q * 16384;
        const int j0 = sub, j1 = 2 + sub;
        dma16(gP + (size_t)j0 * 4096 + off, lb + j0 * 2048 + off);
        dma16(gP + (size_t)j1 * 4096 + off, lb + j1 * 2048 + off);
        dma16(gH + (size_t)j0 * 4096 + off, lb + 8192 + j0 * 2048 + off);
        dma16(gH + (size_t)j1 * 4096 + off, lb + 8192 + j1 * 2048 + off);
    };

    P2W4 P0, P1, P2, H0, H1, H2;
    auto COMP = [&](int q, P2W4& P, P2W4& H) {
        if (!xok) return;
        const __half* sb = (const __half*)(smem + q * 16384);
        p2_partials(sb,        xl, c4, P);
        p2_partials(sb + 4096, xl, c4, H);
    };

    float acc = 0.f;

    ISSUE(0, z0 + 0); ISSUE(1, z0 + 1);   // 8 in flight
    WAITBAR(4);
    COMP(0, P0, H0);
    MIDBAR(); ISSUE(0, z0 + 2);
    WAITBAR(4);
    COMP(1, P1, H1);
    MIDBAR(); ISSUE(1, z0 + 3);

    WAITBAR(4);
    COMP(0, P2, H2);
    if (xok) p2_emit4(P0, P1, P2, H0, H1, H2, acc);
    MIDBAR(); ISSUE(0, z0 + 4);
    WAITBAR(4);
    COMP(1, P0, H0);
    if (xok) p2_emit4(P1, P2, P0, H1, H2, H0, acc);
    MIDBAR(); ISSUE(1, z0 + 5);
    WAITBAR(4);
    COMP(0, P1, H1);
    if (xok) p2_emit4(P2, P0, P1, H2, H0, H1, acc);
    MIDBAR(); ISSUE(0, z0 + 6);           // clamped dummy on last chunk
    WAITBAR(4);
    COMP(1, P2, H2);
    if (xok) p2_emit4(P0, P1, P2, H0, H1, H2, acc);

    asm volatile("s_waitcnt vmcnt(0)" ::: "memory");
    __syncthreads();

    // block reduction (reuse smem, safe after full drain + barrier)
    for (int o = 32; o > 0; o >>= 1) acc += __shfl_down(acc, o, 64);
    float* sred = (float*)smem;
    int* isLast = (int*)(smem + 64);
    double* sd = (double*)(smem + 128);
    const int lane = tid & 63, wv = tid >> 6;
    if (lane == 0) sred[wv] = acc;
    __syncthreads();
    if (tid == 0) {
        float t = 0.f;
#pragma unroll
        for (int i = 0; i < BDIM / 64; ++i) t += sred[i];
        const size_t pidx = (size_t)b * 900 + (size_t)zc * 60 + blockIdx.x;
        __hip_atomic_store(&partial[pidx], t, __ATOMIC_RELAXED,
                           __HIP_MEMORY_SCOPE_AGENT);
        const unsigned old = __hip_atomic_fetch_add(counter, 1u, __ATOMIC_ACQ_REL,
                                                    __HIP_MEMORY_SCOPE_AGENT);
        *isLast = (old == NPART - 1u) ? 1 : 0;
    }
    __syncthreads();

    if (*isLast) {
        double a = 0.0;
        for (unsigned i = tid; i < NPART; i += BDIM)
            a += (double)__hip_atomic_load(&partial[i], __ATOMIC_RELAXED,
                                           __HIP_MEMORY_SCOPE_AGENT);
        for (int o = 32; o > 0; o >>= 1) a += __shfl_down(a, o, 64);
        if (lane == 0) sd[wv] = a;
        __syncthreads();
        if (tid == 0) {
            double t = 0.0;
#pragma unroll
            for (int i = 0; i < BDIM / 64; ++i) t += sd[i];
            out[0] = (float)(t / 13824000.0);
        }
    }
}

extern "C" void kernel_launch(void* const* d_in, const int* in_sizes, int n_in,
                              void* d_out, int out_size, void* d_ws, size_t ws_size,
                              hipStream_t stream)
{
    const float* pred = (const float*)d_in[0];
    const float* hr   = (const float*)d_in[1];

    // ws layout: [0, 7.2KB): 1800 float partials
    //            [32KB): unsigned last-block counter (zeroed by P1(b0))
    //            [64KB, ...): 2 padded fp16 mag buffers (~30 MiB total)
    float* partial = (float*)d_ws;
    unsigned* counter = (unsigned*)((char*)d_ws + 32768);
    __half* magP = (__half*)((char*)d_ws + 65536);
    __half* magH = magP + PMAGSZ;

    for (int b = 0; b < 2; ++b) {
        sobel_mag_v8<<<dim3(31, 8, 2), BDIM, 0, stream>>>(
            pred, hr, magP, magH, b, counter, b == 0 ? 1 : 0);
        sobel2_v8<<<dim3(60, 15), BDIM, 0, stream>>>(
            magP, magH, b, partial, counter, (float*)d_out);
    }
}